// Round 1
// 133.554 us; speedup vs baseline: 1.0321x; 1.0321x over previous
//
#include <hip/hip_runtime.h>
#include <hip/hip_bf16.h>
#include <cstddef>

typedef __attribute__((ext_vector_type(8))) short short8;
typedef __attribute__((ext_vector_type(4))) short short4v;
typedef __attribute__((ext_vector_type(4))) float floatx4;
typedef __hip_bfloat16 bf16;

#define NB 8
#define NC 256
#define ND 128
#define NN 3072
#define NBLK 48           /* proj blocks per batch = NN/64 */
#define BN_EPS 1e-5f

static __device__ __forceinline__ short f2s(float v) {
    bf16 h = __float2bfloat16(v);
    return *reinterpret_cast<short*>(&h);
}

// setup: Wall[r][c] bf16 = [phi_w; g_w; theta_w]  (384 x 256, 192 KB, L2-hot)
__global__ __launch_bounds__(256) void setup_kernel(
    const float* __restrict__ phi_w, const float* __restrict__ g_w,
    const float* __restrict__ theta_w, short* __restrict__ Wall)
{
    int t = threadIdx.x;
    int r = blockIdx.x;
    const float* src = (r < 128) ? (phi_w + (size_t)r * NC)
                     : (r < 256) ? (g_w + (size_t)(r - 128) * NC)
                                 : (theta_w + (size_t)(r - 256) * NC);
    Wall[(size_t)r * NC + t] = f2s(src[t]);
}

// ---------------------------------------------------------------------------
// proj: grid (48, 8), 384 threads = 6 waves; wave w owns rows w*64..w*64+63
// of [phi(0-127); g(128-255); theta(256-383)], n-tile 64.
// R8: T14 async-stage pipeline.
//   - x chunk for kt+1 is loaded into registers DURING kt's MFMA phase
//     (issued AFTER this kt's A-frags so the MFMA's counted vmcnt wait does
//     not drain the prefetch), converted+written to LDS after the barrier.
//   - A-frags for the whole kt are hoisted to right after barrier-1 so their
//     L2 latency hides under the cvt+LDS-write staging phase.
// ---------------------------------------------------------------------------
__global__ __launch_bounds__(384)
void proj_kernel(const float* __restrict__ x, const short* __restrict__ Wall,
                 const float* __restrict__ phi_b, const float* __restrict__ g_b,
                 const float* __restrict__ theta_b,
                 short* __restrict__ thDN, float* __restrict__ Mpart)
{
    __shared__ short PGs[256][72];  // phi/g projections [row][n]
    __shared__ short Xs[64][72];    // x chunk [n][c]
    int b = blockIdx.y;
    int n0 = blockIdx.x * 64;
    int t = threadIdx.x;
    int lane = t & 63;
    int wave = t >> 6;              // 0..5
    int lm = lane & 15;
    int lk = (lane >> 4) * 8;

    const float* xb = x + (size_t)b * NC * NN;

    floatx4 zero = {0.f, 0.f, 0.f, 0.f};
    floatx4 acc[4][4];
#pragma unroll
    for (int i = 0; i < 4; ++i)
#pragma unroll
        for (int j = 0; j < 4; ++j) acc[i][j] = zero;

    // x-stage prefetch registers (threads 0..255 only)
    int sn = t & 63, cg = t >> 6;
    const float* srcp = xb + (size_t)(cg * 16) * NN + n0 + sn;
    float xf[16];
    if (t < 256) {
#pragma unroll
        for (int j = 0; j < 16; ++j) xf[j] = srcp[(size_t)j * NN];
    }

#pragma unroll
    for (int kt = 0; kt < NC; kt += 64) {
        __syncthreads();
        // A-frags for the whole kt (global, L2-hot) — latency hides under
        // the staging phase below.
        short8 af2[2][4];
#pragma unroll
        for (int h = 0; h < 2; ++h)
#pragma unroll
            for (int i = 0; i < 4; ++i)
                af2[h][i] = *(const short8*)(Wall +
                        (size_t)(wave * 64 + i * 16 + lm) * NC + kt + h * 32 + lk);
        // write-late half of the x stage: convert prefetched regs -> LDS
        if (t < 256) {
            short8 s0, s1;
#pragma unroll
            for (int j = 0; j < 8; ++j) {
                s0[j] = f2s(xf[j]);
                s1[j] = f2s(xf[8 + j]);
            }
            *(short8*)&Xs[sn][cg * 16]     = s0;
            *(short8*)&Xs[sn][cg * 16 + 8] = s1;
        }
        __syncthreads();
        // issue-early half for kt+1: HBM latency hides under the MFMAs.
        // (Issued after af2 so waiting on af2 leaves these in flight.)
        if (t < 256 && kt < NC - 64) {
            const float* np = srcp + (size_t)(kt + 64) * NN;
#pragma unroll
            for (int j = 0; j < 16; ++j) xf[j] = np[(size_t)j * NN];
        }
#pragma unroll
        for (int h = 0; h < 2; ++h) {
            int kk = h * 32;
            short8 bfr[4];
#pragma unroll
            for (int j = 0; j < 4; ++j)
                bfr[j] = *(const short8*)&Xs[j * 16 + lm][kk + lk];
#pragma unroll
            for (int i = 0; i < 4; ++i)
#pragma unroll
                for (int j = 0; j < 4; ++j)
                    acc[i][j] = __builtin_amdgcn_mfma_f32_16x16x32_bf16(
                        af2[h][i], bfr[j], acc[i][j], 0, 0, 0);
        }
    }

    // C/D layout: col = lane&15, row = (lane>>4)*4 + reg
    int row0 = wave * 64 + (lane >> 4) * 4;

    if (wave < 4) {    // phi/g: +bias -> PGs[row][n]
#pragma unroll
        for (int i = 0; i < 4; ++i) {
#pragma unroll
            for (int r = 0; r < 4; ++r) {
                int row = row0 + i * 16 + r;
                float bv = (row < 128) ? phi_b[row] : g_b[row - 128];
#pragma unroll
                for (int j = 0; j < 4; ++j)
                    PGs[row][lm + j * 16] = f2s(acc[i][j][r] + bv);
            }
        }
    } else {           // theta: +bias -> thDN[b][d][n]  (lane-contiguous)
        short* Tb = thDN + (size_t)b * ND * NN;
#pragma unroll
        for (int i = 0; i < 4; ++i) {
#pragma unroll
            for (int r = 0; r < 4; ++r) {
                int d = row0 - 256 + i * 16 + r;
                float bv = theta_b[d];
#pragma unroll
                for (int j = 0; j < 4; ++j)
                    Tb[(size_t)d * NN + n0 + lm + j * 16] =
                        f2s(acc[i][j][r] + bv);
            }
        }
    }
    __syncthreads();

    // M partial: waves 0-3 compute 64x64 tiles of phi . g^T over K=n=64,
    // write to private slot Mpart[b][blockIdx.x][.] (coalesced, no atomics)
    if (wave < 4) {
        int wr = wave >> 1, wc = wave & 1;
        floatx4 macc[4][4];
#pragma unroll
        for (int i = 0; i < 4; ++i)
#pragma unroll
            for (int j = 0; j < 4; ++j) macc[i][j] = zero;
#pragma unroll
        for (int kk = 0; kk < 64; kk += 32) {
            short8 af[4], bfr[4];
#pragma unroll
            for (int i = 0; i < 4; ++i)
                af[i] = *(const short8*)&PGs[wr * 64 + i * 16 + lm][kk + lk];
#pragma unroll
            for (int j = 0; j < 4; ++j)
                bfr[j] = *(const short8*)&PGs[128 + wc * 64 + j * 16 + lm][kk + lk];
#pragma unroll
            for (int i = 0; i < 4; ++i)
#pragma unroll
                for (int j = 0; j < 4; ++j)
                    macc[i][j] = __builtin_amdgcn_mfma_f32_16x16x32_bf16(
                        af[i], bfr[j], macc[i][j], 0, 0, 0);
        }
        float* Mf = Mpart + ((size_t)b * NBLK + blockIdx.x) * (ND * ND);
        int mr0 = wr * 64 + (lane >> 4) * 4;
        int mc0 = wc * 64 + lm;
        const float sc = 1.f / (float)NN;
#pragma unroll
        for (int i = 0; i < 4; ++i)
#pragma unroll
            for (int j = 0; j < 4; ++j)
#pragma unroll
                for (int r = 0; r < 4; ++r)
                    Mf[(size_t)(mr0 + i * 16 + r) * ND + mc0 + j * 16] =
                        macc[i][j][r] * sc;
    }
}

// reduce: Mb16[b][e][d] = bf16( sum_p Mpart[b][p][e][d] )
// R8: float4-wide (1 KB/wave/instr), unroll 12; grid 128 x 256 threads,
// four output elements per thread; fully coalesced.
__global__ __launch_bounds__(256)
void reduce_kernel(const float* __restrict__ Mpart, short* __restrict__ Mb16)
{
    int idx4 = (blockIdx.x * 256 + threadIdx.x) * 4;   // 0 .. 131068
    const float* src = Mpart + (size_t)(idx4 >> 14) * (NBLK * 16384)
                             + (idx4 & 16383);
    floatx4 s = {0.f, 0.f, 0.f, 0.f};
#pragma unroll 12
    for (int p = 0; p < NBLK; ++p)
        s += *(const floatx4*)(src + (size_t)p * 16384);
    short4v o;
#pragma unroll
    for (int j = 0; j < 4; ++j) o[j] = f2s(s[j]);
    *(short4v*)(Mb16 + idx4) = o;
}

// ---------------------------------------------------------------------------
// final: grid (24, 2, 8), 256 threads.
// R8: T14 async-stage pipeline on both stages.
//   Stage 1: w_w/Mb16 tiles preloaded into regs before the loop; next tile
//     issued during the MFMA phase; thDN tile for stage-2 kt=0 issued during
//     stage-1's second MFMA phase.
//   Stage 2: thDN tile for kt=64 issued during kt=0's MFMA phase.
// ---------------------------------------------------------------------------
__global__ __launch_bounds__(256)
void final_kernel(const short* __restrict__ Mb16, const short* __restrict__ thDN,
                  const float* __restrict__ w_w, const float* __restrict__ w_b,
                  const float* __restrict__ gamma, const float* __restrict__ beta,
                  const float* __restrict__ mean, const float* __restrict__ var,
                  const float* __restrict__ x, float* __restrict__ out)
{
    __shared__ short As[128][72];
    __shared__ short Bs[128][72];
    __shared__ short P2s[128][136];
    int b = blockIdx.z;
    int tile_m = blockIdx.y * 128;   // c tile
    int tile_n = blockIdx.x * 128;   // n tile
    int t = threadIdx.x;
    int lane = t & 63;
    int wave = t >> 6;
    int wr = wave >> 1, wc = wave & 1;
    int lm = lane & 15;
    int lk = (lane >> 4) * 8;
    int ch = (t & 7) * 8;
    int r0 = t >> 3;
    int dl = t & 63;
    int ng = t >> 6;

    const short* Mb = Mb16 + (size_t)b * ND * ND;
    const short* Tb = thDN + (size_t)b * ND * NN;
    const short* tsrc = Tb + (size_t)dl * NN + tile_n + ng * 32;

    floatx4 zero = {0.f, 0.f, 0.f, 0.f};
    floatx4 acc[4][4];
#pragma unroll
    for (int i = 0; i < 4; ++i)
#pragma unroll
        for (int j = 0; j < 4; ++j) acc[i][j] = zero;

    // stage-1 preload (kt = 0)
    floatx4 av0[4], av1[4];
    short8 bv[4];
#pragma unroll
    for (int p = 0; p < 4; ++p) {
        int r = r0 + p * 32;
        const float* ap = w_w + (size_t)(tile_m + r) * ND + ch;
        av0[p] = *(const floatx4*)ap;
        av1[p] = *(const floatx4*)(ap + 4);
        bv[p]  = *(const short8*)(Mb + (size_t)r * ND + ch);
    }
    short8 tv[4];

    // ---- stage 1: P2tile = w_w(c,d) . M(e,d)^T, K = d = 128
#pragma unroll
    for (int kt = 0; kt < ND; kt += 64) {
        __syncthreads();
#pragma unroll
        for (int p = 0; p < 4; ++p) {
            int r = r0 + p * 32;
            short8 sa;
#pragma unroll
            for (int j = 0; j < 4; ++j) {
                sa[j]     = f2s(av0[p][j]);
                sa[4 + j] = f2s(av1[p][j]);
            }
            *(short8*)&As[r][ch] = sa;
            *(short8*)&Bs[r][ch] = bv[p];
        }
        __syncthreads();
        if (kt == 0) {          // prefetch stage-1 kt=64
#pragma unroll
            for (int p = 0; p < 4; ++p) {
                int r = r0 + p * 32;
                const float* ap = w_w + (size_t)(tile_m + r) * ND + 64 + ch;
                av0[p] = *(const floatx4*)ap;
                av1[p] = *(const floatx4*)(ap + 4);
                bv[p]  = *(const short8*)(Mb + (size_t)r * ND + 64 + ch);
            }
        } else {                // prefetch stage-2 kt=0 (thDN)
#pragma unroll
            for (int q = 0; q < 4; ++q)
                tv[q] = *(const short8*)(tsrc + q * 8);
        }
#pragma unroll
        for (int kk = 0; kk < 64; kk += 32) {
            short8 af[4], bfr[4];
#pragma unroll
            for (int i = 0; i < 4; ++i)
                af[i] = *(const short8*)&As[wr * 64 + i * 16 + lm][kk + lk];
#pragma unroll
            for (int j = 0; j < 4; ++j)
                bfr[j] = *(const short8*)&Bs[wc * 64 + j * 16 + lm][kk + lk];
#pragma unroll
            for (int i = 0; i < 4; ++i)
#pragma unroll
                for (int j = 0; j < 4; ++j)
                    acc[i][j] = __builtin_amdgcn_mfma_f32_16x16x32_bf16(
                        af[i], bfr[j], acc[i][j], 0, 0, 0);
        }
    }

    // scale by inv[c], deposit P2s[c_local][e] (A-operand layout for stage 2)
    {
        int row0 = wr * 64 + (lane >> 4) * 4;
        int col0 = wc * 64 + lm;
#pragma unroll
        for (int i = 0; i < 4; ++i) {
#pragma unroll
            for (int r = 0; r < 4; ++r) {
                int cl = row0 + i * 16 + r;
                int c = tile_m + cl;
                float iv = gamma[c] * rsqrtf(var[c] + BN_EPS);
#pragma unroll
                for (int j = 0; j < 4; ++j)
                    P2s[cl][col0 + j * 16] = f2s(acc[i][j][r] * iv);
            }
        }
    }

    // ---- stage 2: out = P2 . theta^T, K = e = 128; theta from thDN[d][n]
    floatx4 acc2[4][4];
#pragma unroll
    for (int i = 0; i < 4; ++i)
#pragma unroll
        for (int j = 0; j < 4; ++j) acc2[i][j] = zero;

#pragma unroll
    for (int kt = 0; kt < ND; kt += 64) {
        __syncthreads();
        // write-late: Bs[n(128)][d(64)] transpose from prefetched regs
#pragma unroll
        for (int q = 0; q < 4; ++q)
#pragma unroll
            for (int jj = 0; jj < 8; ++jj)
                Bs[ng * 32 + q * 8 + jj][dl] = tv[q][jj];
        __syncthreads();
        if (kt == 0) {          // issue-early: thDN kt=64
#pragma unroll
            for (int q = 0; q < 4; ++q)
                tv[q] = *(const short8*)(tsrc + (size_t)64 * NN + q * 8);
        }
#pragma unroll
        for (int kk = 0; kk < 64; kk += 32) {
            short8 af[4], bfr[4];
#pragma unroll
            for (int i = 0; i < 4; ++i)
                af[i] = *(const short8*)&P2s[wr * 64 + i * 16 + lm][kt + kk + lk];
#pragma unroll
            for (int j = 0; j < 4; ++j)
                bfr[j] = *(const short8*)&Bs[wc * 64 + j * 16 + lm][kk + lk];
#pragma unroll
            for (int i = 0; i < 4; ++i)
#pragma unroll
                for (int j = 0; j < 4; ++j)
                    acc2[i][j] = __builtin_amdgcn_mfma_f32_16x16x32_bf16(
                        af[i], bfr[j], acc2[i][j], 0, 0, 0);
        }
    }

    // epilogue: + bias2[c] + x residual -> fp32 out
    int crow0 = tile_m + wr * 64 + (lane >> 4) * 4;
    int col0 = tile_n + wc * 64 + lm;
    float* Cf = out + (size_t)b * NC * NN;
    const float* Rg = x + (size_t)b * NC * NN;
#pragma unroll
    for (int i = 0; i < 4; ++i) {
#pragma unroll
        for (int r = 0; r < 4; ++r) {
            int c = crow0 + i * 16 + r;
            float iv = gamma[c] * rsqrtf(var[c] + BN_EPS);
            float b2 = iv * (w_b[c] - mean[c]) + beta[c];
#pragma unroll
            for (int j = 0; j < 4; ++j) {
                size_t idx = (size_t)c * NN + col0 + j * 16;
                Cf[idx] = acc2[i][j][r] + b2 + Rg[idx];
            }
        }
    }
}

extern "C" void kernel_launch(void* const* d_in, const int* in_sizes, int n_in,
                              void* d_out, int out_size, void* d_ws, size_t ws_size,
                              hipStream_t stream)
{
    const float* x       = (const float*)d_in[0];
    const float* g_w     = (const float*)d_in[1];
    const float* g_b     = (const float*)d_in[2];
    const float* theta_w = (const float*)d_in[3];
    const float* theta_b = (const float*)d_in[4];
    const float* phi_w   = (const float*)d_in[5];
    const float* phi_b   = (const float*)d_in[6];
    const float* w_w     = (const float*)d_in[7];
    const float* w_b     = (const float*)d_in[8];
    const float* gamma   = (const float*)d_in[9];
    const float* beta    = (const float*)d_in[10];
    const float* mean    = (const float*)d_in[11];
    const float* var     = (const float*)d_in[12];
    (void)in_sizes; (void)n_in; (void)out_size; (void)ws_size;

    char* w = (char*)d_ws;
    short* thDN  = (short*)w; w += (size_t)NB * ND * NN * 2;         // 6.3 MB
    float* Mpart = (float*)w; w += (size_t)NB * NBLK * ND * ND * 4;  // 25.2 MB
    short* Mb16  = (short*)w; w += (size_t)NB * ND * ND * 2;         // 256 KB
    short* Wall  = (short*)w; w += (size_t)384 * NC * 2;             // 192 KB

    setup_kernel<<<dim3(384), dim3(256), 0, stream>>>(
        phi_w, g_w, theta_w, Wall);

    proj_kernel<<<dim3(NN / 64, NB), dim3(384), 0, stream>>>(
        x, Wall, phi_b, g_b, theta_b, thDN, Mpart);

    reduce_kernel<<<dim3(128), dim3(256), 0, stream>>>(Mpart, Mb16);

    final_kernel<<<dim3(NN / 128, NC / 128, NB), 256, 0, stream>>>(
        Mb16, thDN, w_w, w_b, gamma, beta, mean, var, x, (float*)d_out);
}